// Round 4
// baseline (166.315 us; speedup 1.0000x reference)
//
#include <hip/hip_runtime.h>
#include <hip/hip_bf16.h>

namespace {
constexpr int N_ = 4, H_ = 512, W_ = 512, K_ = 4;
constexpr float SIGMA_ = 1e-4f;
constexpr float GAMMA_ = 1e-4f;
constexpr float EPS_   = 1e-10f;
constexpr float ZNEAR_ = 1.0f, ZFAR_ = 100.0f;

// 4-byte-aligned vector types: gfx9+ global_load_dwordx4 only needs dword
// alignment, and faces/vnorm/bary rows are 12 B (4-byte aligned) apart.
typedef float f32x4 __attribute__((ext_vector_type(4), aligned(4)));
typedef int   i32x4 __attribute__((ext_vector_type(4), aligned(4)));
} // namespace

// R3 counters: 60us, FETCH 105MB (== ideal, tables L2-resident), 2.0TB/s (25%),
// VALUBusy 10%, occ 70% -> TA/L1 address-divergence bound: 15 scalar dword
// gathers per contributing slot ~= 990 line-probes/wave. This round: vectorize
// gathers (15 -> ~6 probes/slot) + nontemporal hints on the 105MB stream so it
// doesn't evict the 3.6MB faces/vnorm tables from L2.
__global__ __launch_bounds__(256) void normal_shader_kernel(
    const float* __restrict__ vnorm,
    const float* __restrict__ bary,
    const float* __restrict__ dists,
    const float* __restrict__ zbuf,
    const int*   __restrict__ faces,
    const int*   __restrict__ ptf,
    float*       __restrict__ out,
    int P)
{
    const int p = blockIdx.x * blockDim.x + threadIdx.x;
    if (p >= P) return;

    const i32x4 f4 = __builtin_nontemporal_load(reinterpret_cast<const i32x4*>(ptf) + p);
    const int fidx[4] = {f4.x, f4.y, f4.z, f4.w};

    const f32x4 dv = __builtin_nontemporal_load(reinterpret_cast<const f32x4*>(dists) + p);
    const f32x4 zv = __builtin_nontemporal_load(reinterpret_cast<const f32x4*>(zbuf) + p);
    const float d[4] = {dv.x, dv.y, dv.z, dv.w};
    const float z[4] = {zv.x, zv.y, zv.z, zv.w};

    float prob[4], zinv[4];
    float zmax = EPS_;
#pragma unroll
    for (int k = 0; k < K_; ++k) {
        const bool valid = fidx[k] >= 0;
        // sigmoid(-d/sigma) = 1/(1+exp(d/sigma)); masked to 0 when invalid
        prob[k] = valid ? 1.0f / (1.0f + __expf(d[k] * (1.0f / SIGMA_))) : 0.0f;
        zinv[k] = valid ? (ZFAR_ - z[k]) * (1.0f / (ZFAR_ - ZNEAR_)) : 0.0f;
        zmax = fmaxf(zmax, zinv[k]);
    }
    const float delta = fmaxf(__expf((EPS_ - zmax) * (1.0f / GAMMA_)), EPS_);

    float acc0 = 0.f, acc1 = 0.f, acc2 = 0.f, wsum = 0.f;
#pragma unroll
    for (int k = 0; k < K_; ++k) {
        const float wn = prob[k] * __expf((zinv[k] - zmax) * (1.0f / GAMMA_));
        wsum += wn;
        // wn == 0 (invalid face, or exp underflow: zinv < zmax - ~0.0087)
        // contributes exactly 0 in the reference -> skipping gathers is
        // bit-equivalent. ~1 of 4 faces survives the /1e-4 softmax.
        if (wn != 0.0f) {
            // faces row [3 ints] as one int4 (4th element unused; <=4B overread
            // stays in the allocation's page).
            const i32x4 fv = *reinterpret_cast<const i32x4*>(faces + 3 * (size_t)fidx[k]);

            const f32x4 bv = __builtin_nontemporal_load(
                reinterpret_cast<const f32x4*>(bary + ((size_t)p * 4 + k) * 3));
            const float b0 = bv.x, b1 = bv.y, b2 = bv.z;

            // vnorm rows [3 floats] as float4 each (1 line-probe instead of 3).
            const f32x4 n0 = *reinterpret_cast<const f32x4*>(vnorm + 3 * (size_t)fv.x);
            const f32x4 n1 = *reinterpret_cast<const f32x4*>(vnorm + 3 * (size_t)fv.y);
            const f32x4 n2 = *reinterpret_cast<const f32x4*>(vnorm + 3 * (size_t)fv.z);

            acc0 += wn * (b0 * n0.x + b1 * n1.x + b2 * n2.x);
            acc1 += wn * (b0 * n0.y + b1 * n1.y + b2 * n2.y);
            acc2 += wn * (b0 * n0.z + b1 * n1.z + b2 * n2.z);
        }
    }

    const float inv_denom = 1.0f / (wsum + delta);
    const float r0 = (acc0 + delta) * inv_denom;   // bg = (1,1,1)
    const float r1 = (acc1 + delta) * inv_denom;
    const float r2 = (acc2 + delta) * inv_denom;
    const float nrm = fmaxf(sqrtf(r0 * r0 + r1 * r1 + r2 * r2), 1e-12f);
    const float inv = 1.0f / nrm;

    float* op = out + (size_t)p * 3;
    __builtin_nontemporal_store(r0 * inv, op + 0);
    __builtin_nontemporal_store(r1 * inv, op + 1);
    __builtin_nontemporal_store(r2 * inv, op + 2);
}

extern "C" void kernel_launch(void* const* d_in, const int* in_sizes, int n_in,
                              void* d_out, int out_size, void* d_ws, size_t ws_size,
                              hipStream_t stream) {
    // setup_inputs order: verts(0, unused), vertex_normals(1), bary_coords(2),
    // dists(3), zbuf(4), faces(5), pix_to_face(6)
    const float* vnorm = (const float*)d_in[1];
    const float* bary  = (const float*)d_in[2];
    const float* dists = (const float*)d_in[3];
    const float* zbuf  = (const float*)d_in[4];
    const int*   faces = (const int*)d_in[5];
    const int*   ptf   = (const int*)d_in[6];
    float*       out   = (float*)d_out;

    const int P = N_ * H_ * W_;
    const dim3 block(256);
    const dim3 grid((P + block.x - 1) / block.x);
    hipLaunchKernelGGL(normal_shader_kernel, grid, block, 0, stream,
                       vnorm, bary, dists, zbuf, faces, ptf, out, P);
}

// Round 5
// 164.442 us; speedup vs baseline: 1.0114x; 1.0114x over previous
//
#include <hip/hip_runtime.h>
#include <hip/hip_bf16.h>

namespace {
constexpr int N_ = 4, H_ = 512, W_ = 512, K_ = 4;
constexpr float SIGMA_ = 1e-4f;
constexpr float GAMMA_ = 1e-4f;
constexpr float EPS_   = 1e-10f;
constexpr float ZNEAR_ = 1.0f, ZFAR_ = 100.0f;

// 4-byte-aligned vector types: gfx9 dwordx4 needs only dword alignment.
typedef float f32x4 __attribute__((ext_vector_type(4), aligned(4)));
typedef int   i32x4 __attribute__((ext_vector_type(4), aligned(4)));
} // namespace

// R4 post-mortem: probe-count cut (15->5 loads/slot) gained only 9% => not
// TA-probe bound. Latency-chain bound: each `if(wn!=0)` block forces
// s_waitcnt vmcnt(0) before its FMAs -> 4 serial (faces->vnorm) chains
// ~2400 cyc/wave, ~5 waves/SIMD can't hide it. This round: NO branches.
// Dead lanes clamp their face index to 0 (gather becomes a broadcast; result
// killed by wn==0 exactly, 0*finite==0 == reference). All 4 faces-gathers
// issue together, then all 12 vnorm-gathers, then math: critical path drops
// from 8 dependent gather latencies to 2.
__global__ __launch_bounds__(256) void normal_shader_kernel(
    const float* __restrict__ vnorm,
    const float* __restrict__ bary,
    const float* __restrict__ dists,
    const float* __restrict__ zbuf,
    const int*   __restrict__ faces,
    const int*   __restrict__ ptf,
    float*       __restrict__ out,
    int P)
{
    const int p = blockIdx.x * blockDim.x + threadIdx.x;
    if (p >= P) return;

    const i32x4 f4 = __builtin_nontemporal_load(reinterpret_cast<const i32x4*>(ptf) + p);
    const int fidx[4] = {f4.x, f4.y, f4.z, f4.w};

    const f32x4 dv = __builtin_nontemporal_load(reinterpret_cast<const f32x4*>(dists) + p);
    const f32x4 zv = __builtin_nontemporal_load(reinterpret_cast<const f32x4*>(zbuf) + p);
    const float d[4] = {dv.x, dv.y, dv.z, dv.w};
    const float z[4] = {zv.x, zv.y, zv.z, zv.w};

    float prob[4], zinv[4];
    float zmax = EPS_;
#pragma unroll
    for (int k = 0; k < K_; ++k) {
        const bool valid = fidx[k] >= 0;
        prob[k] = valid ? 1.0f / (1.0f + __expf(d[k] * (1.0f / SIGMA_))) : 0.0f;
        zinv[k] = valid ? (ZFAR_ - z[k]) * (1.0f / (ZFAR_ - ZNEAR_)) : 0.0f;
        zmax = fmaxf(zmax, zinv[k]);
    }
    const float delta = fmaxf(__expf((EPS_ - zmax) * (1.0f / GAMMA_)), EPS_);

    float wn[4];
#pragma unroll
    for (int k = 0; k < K_; ++k)
        wn[k] = prob[k] * __expf((zinv[k] - zmax) * (1.0f / GAMMA_));

    // Clamp dead slots (invalid face or softmax underflow, ~3 of 4) to face 0:
    // their lanes gather a broadcast line and contribute wn*x = 0 exactly.
    int cl[4];
#pragma unroll
    for (int k = 0; k < K_; ++k)
        cl[k] = (wn[k] != 0.0f) ? fidx[k] : 0;

    // Phase 1: all face-row gathers (independent). 4th int of row overreads
    // 4B within the allocation page; never used as an index below.
    i32x4 fv[4];
#pragma unroll
    for (int k = 0; k < K_; ++k)
        fv[k] = *reinterpret_cast<const i32x4*>(faces + 3 * (size_t)cl[k]);

    // Full bary row (48B = all 4 slots) as 3 aligned float4s, unconditional.
    const f32x4* bp = reinterpret_cast<const f32x4*>(bary + (size_t)p * 12);
    const f32x4 bA = __builtin_nontemporal_load(bp + 0);
    const f32x4 bB = __builtin_nontemporal_load(bp + 1);
    const f32x4 bC = __builtin_nontemporal_load(bp + 2);
    const float bb[12] = {bA.x, bA.y, bA.z, bA.w,
                          bB.x, bB.y, bB.z, bB.w,
                          bC.x, bC.y, bC.z, bC.w};

    // Phase 2: all 12 vertex-normal gathers (independent; one dependency step
    // after fv). 12B rows read as float4; w lane-overread is page-safe.
    f32x4 n0[4], n1[4], n2[4];
#pragma unroll
    for (int k = 0; k < K_; ++k) {
        n0[k] = *reinterpret_cast<const f32x4*>(vnorm + 3 * (size_t)fv[k].x);
        n1[k] = *reinterpret_cast<const f32x4*>(vnorm + 3 * (size_t)fv[k].y);
        n2[k] = *reinterpret_cast<const f32x4*>(vnorm + 3 * (size_t)fv[k].z);
    }

    // Phase 3: pure math.
    float acc0 = 0.f, acc1 = 0.f, acc2 = 0.f, wsum = 0.f;
#pragma unroll
    for (int k = 0; k < K_; ++k) {
        wsum += wn[k];
        const float b0 = bb[3 * k + 0], b1 = bb[3 * k + 1], b2 = bb[3 * k + 2];
        acc0 += wn[k] * (b0 * n0[k].x + b1 * n1[k].x + b2 * n2[k].x);
        acc1 += wn[k] * (b0 * n0[k].y + b1 * n1[k].y + b2 * n2[k].y);
        acc2 += wn[k] * (b0 * n0[k].z + b1 * n1[k].z + b2 * n2[k].z);
    }

    const float inv_denom = 1.0f / (wsum + delta);
    const float r0 = (acc0 + delta) * inv_denom;   // bg = (1,1,1)
    const float r1 = (acc1 + delta) * inv_denom;
    const float r2 = (acc2 + delta) * inv_denom;
    const float nrm = fmaxf(sqrtf(r0 * r0 + r1 * r1 + r2 * r2), 1e-12f);
    const float inv = 1.0f / nrm;

    float* op = out + (size_t)p * 3;
    __builtin_nontemporal_store(r0 * inv, op + 0);
    __builtin_nontemporal_store(r1 * inv, op + 1);
    __builtin_nontemporal_store(r2 * inv, op + 2);
}

extern "C" void kernel_launch(void* const* d_in, const int* in_sizes, int n_in,
                              void* d_out, int out_size, void* d_ws, size_t ws_size,
                              hipStream_t stream) {
    // setup_inputs order: verts(0, unused), vertex_normals(1), bary_coords(2),
    // dists(3), zbuf(4), faces(5), pix_to_face(6)
    const float* vnorm = (const float*)d_in[1];
    const float* bary  = (const float*)d_in[2];
    const float* dists = (const float*)d_in[3];
    const float* zbuf  = (const float*)d_in[4];
    const int*   faces = (const int*)d_in[5];
    const int*   ptf   = (const int*)d_in[6];
    float*       out   = (float*)d_out;

    const int P = N_ * H_ * W_;
    const dim3 block(256);
    const dim3 grid((P + block.x - 1) / block.x);
    hipLaunchKernelGGL(normal_shader_kernel, grid, block, 0, stream,
                       vnorm, bary, dists, zbuf, faces, ptf, out, P);
}